// Round 1
// baseline (73.371 us; speedup 1.0000x reference)
//
#include <hip/hip_runtime.h>
#include <math.h>

// Problem constants (from reference setup_inputs): N=4096 rows, S=128 samples.
#define S 128
#define NROWS 4096

// One block (128 threads = 2 waves) per row.
// Computes: bestShift (argmin over circular shifts of L2 distance),
// |scale-1|, per-row detail norm sqrt(sum g^2), per-row MSE partial sum.
__global__ __launch_bounds__(S) void loss3_row_kernel(
    const float* __restrict__ outp,
    const float* __restrict__ trp,
    float* __restrict__ rowres /* [NROWS][4] */) {

    __shared__ float s_out[S];
    __shared__ float s_tr[S];
    __shared__ float red_v[S];
    __shared__ int   red_i[S];

    const int n = blockIdx.x;
    const int t = threadIdx.x;

    const float* orow = outp + (size_t)n * S;
    const float* trow = trp  + (size_t)n * S;
    const float ov = orow[t];
    const float tv = trow[t];
    s_out[t] = ov;
    s_tr[t]  = tv;
    __syncthreads();

    // ---- shiftDiff^2 for shift a = t:
    // shifted[a][b] = out[(b - a) mod S]; acc = sum_b (shifted - tr[b])^2
    // Lane addresses at fixed b are consecutive mod 128 -> conflict-free LDS.
    float acc = 0.f;
    #pragma unroll 16
    for (int b = 0; b < S; ++b) {
        float d = s_out[(b - t) & (S - 1)] - s_tr[b];
        acc = fmaf(d, d, acc);
    }

    // ---- argmin across the 128 shifts; tie-break to the SMALLEST index
    // (matches jnp.argmin "first occurrence" semantics; sqrt is monotone so
    //  comparing squared sums gives the same argmin).
    red_v[t] = acc;
    red_i[t] = t;
    __syncthreads();
    for (int off = S / 2; off > 0; off >>= 1) {
        if (t < off) {
            float v2 = red_v[t + off];
            int   i2 = red_i[t + off];
            if (v2 < red_v[t] || (v2 == red_v[t] && i2 < red_i[t])) {
                red_v[t] = v2;
                red_i[t] = i2;
            }
        }
        __syncthreads();
    }
    const int bestShift = red_i[0];
    __syncthreads();

    // ---- row peaks. Note max(rolled row) == max(original row) (permutation).
    red_v[t] = ov;
    __syncthreads();
    for (int off = S / 2; off > 0; off >>= 1) {
        if (t < off) red_v[t] = fmaxf(red_v[t], red_v[t + off]);
        __syncthreads();
    }
    const float outPeak = red_v[0];
    __syncthreads();

    red_v[t] = tv;
    __syncthreads();
    for (int off = S / 2; off > 0; off >>= 1) {
        if (t < off) red_v[t] = fmaxf(red_v[t], red_v[t + off]);
        __syncthreads();
    }
    const float trPeak = red_v[0];
    __syncthreads();

    const float scale = trPeak / outPeak;

    // ---- detail term: g = cgrad(rolled*scale) - cgrad(truth), circular.
    // rolled[b] = out[(b - bestShift) mod S]. Mirror the reference: scale
    // each rolled sample FIRST, then take the circular second difference.
    const float r0 = s_out[(t     - bestShift) & (S - 1)] * scale;
    const float rm = s_out[(t - 1 - bestShift) & (S - 1)] * scale;
    const float rp = s_out[(t + 1 - bestShift) & (S - 1)] * scale;
    const float cgo = r0 - 0.5f * (rm + rp);
    const float tm = s_tr[(t - 1) & (S - 1)];
    const float tp = s_tr[(t + 1) & (S - 1)];
    const float cgt = tv - 0.5f * (tm + tp);
    const float g  = cgo - cgt;
    const float d0 = ov - tv;

    // ---- reduce sum(g^2) then sum((out-tr)^2)
    red_v[t] = g * g;
    __syncthreads();
    for (int off = S / 2; off > 0; off >>= 1) {
        if (t < off) red_v[t] += red_v[t + off];
        __syncthreads();
    }
    const float gsum = red_v[0];
    __syncthreads();

    red_v[t] = d0 * d0;
    __syncthreads();
    for (int off = S / 2; off > 0; off >>= 1) {
        if (t < off) red_v[t] += red_v[t + off];
        __syncthreads();
    }
    const float msesum = red_v[0];

    if (t == 0) {
        float* r = rowres + 4 * (size_t)n;
        r[0] = (float)bestShift;        // lossLoc contribution (exact int)
        r[1] = fabsf(scale - 1.0f);     // lossTime contribution
        r[2] = sqrtf(gsum);             // lossDetail contribution
        r[3] = msesum;                  // lossMSE partial (sqrt at the end)
    }
}

// Deterministic final reduction over the 4096 row records -> scalar loss.
__global__ __launch_bounds__(256) void loss3_reduce_kernel(
    const float* __restrict__ rowres, float* __restrict__ out) {

    __shared__ double sh0[256];
    __shared__ double sh1[256];
    __shared__ double sh2[256];
    __shared__ double sh3[256];

    const int t = threadIdx.x;
    double sLoc = 0.0, sTime = 0.0, sDet = 0.0, sMse = 0.0;
    for (int n = t; n < NROWS; n += 256) {
        const float* r = rowres + 4 * (size_t)n;
        sLoc  += (double)r[0];
        sTime += (double)r[1];
        sDet  += (double)r[2];
        sMse  += (double)r[3];
    }
    sh0[t] = sLoc; sh1[t] = sTime; sh2[t] = sDet; sh3[t] = sMse;
    __syncthreads();
    for (int off = 128; off > 0; off >>= 1) {
        if (t < off) {
            sh0[t] += sh0[t + off];
            sh1[t] += sh1[t + off];
            sh2[t] += sh2[t + off];
            sh3[t] += sh3[t + off];
        }
        __syncthreads();
    }
    if (t == 0) {
        double loss = 50.0 * sh0[0] + 100.0 * sh1[0] + 0.1 * sh2[0]
                    + sqrt(sh3[0]);
        out[0] = (float)loss;
    }
}

extern "C" void kernel_launch(void* const* d_in, const int* in_sizes, int n_in,
                              void* d_out, int out_size, void* d_ws, size_t ws_size,
                              hipStream_t stream) {
    const float* outp = (const float*)d_in[0];  // 'output' (N,S) fp32
    const float* trp  = (const float*)d_in[1];  // 'truth'  (N,S) fp32
    float* res        = (float*)d_out;          // scalar fp32
    float* rowres     = (float*)d_ws;           // NROWS*4 floats = 64 KiB

    loss3_row_kernel<<<NROWS, S, 0, stream>>>(outp, trp, rowres);
    loss3_reduce_kernel<<<1, 256, 0, stream>>>(rowres, res);
}